// Round 8
// baseline (60.095 us; speedup 1.0000x reference)
//
#include <hip/hip_runtime.h>

// Dynamic lightweight convolution, 3-kernel split. B=8,S=2048,D=1024,K=7,H=16,L=2042.
// wprep: WtFrag[i=7][ks=32][lane=64] x 8bf16 = W[ks*32+(lane>>4)*8+j][i*16+(lane&15)]
// pgemm: per wave = 16 rows, barrier-free: A-frags direct from global -> 7x32 MFMA
//        -> in-reg softmax -> wave-private LDS transpose -> P stored in out[b][l][0:112]
// conv : per block = 8 rows x 1024 d: P->LDS, barrier, 14 x-loads/thread, FMA, store.

#define KK 7
#define HH 16
#define DD 1024
#define SS 2048
#define LL 2042
#define NO 112
#define WTF_BYTES (7 * 32 * 64 * 8 * 2)      // 229376

typedef __attribute__((ext_vector_type(8))) short bf16x8;
typedef __attribute__((ext_vector_type(4))) float f32x4;

__device__ __forceinline__ unsigned short f2bf(float f) {
    unsigned u = __builtin_bit_cast(unsigned, f);
    u += 0x7fffu + ((u >> 16) & 1u);         // RNE
    return (unsigned short)(u >> 16);
}
__device__ __forceinline__ unsigned bfpack(float lo, float hi) {
    return (unsigned)f2bf(lo) | ((unsigned)f2bf(hi) << 16);
}

__global__ void wprep(const float* __restrict__ W, unsigned short* __restrict__ wtf) {
    const int bx = blockIdx.x;               // 0..223 = i*32 + ks
    const int lane = threadIdx.x;
    const int i = bx >> 5, ks = bx & 31;
    const int frow = lane & 15, fq = lane >> 4;
    const int col = i * 16 + frow;
    const int k0 = ks * 32 + fq * 8;
    unsigned p[4];
#pragma unroll
    for (int j = 0; j < 4; ++j) {
        float a = W[(size_t)(k0 + 2 * j) * NO + col];
        float b = W[(size_t)(k0 + 2 * j + 1) * NO + col];
        p[j] = bfpack(a, b);
    }
    *(uint4*)(wtf + (size_t)(bx * 64 + lane) * 8) = make_uint4(p[0], p[1], p[2], p[3]);
}

// pgemm: block = 256 thr = 4 waves, wave = 16 rows. LDS: 4*16*112 f32 = 28672 B.
template <bool WSOK>
__global__ __launch_bounds__(256, 4)
void pgemm(const float* __restrict__ x, const float* __restrict__ W,
           const float* __restrict__ bias, const unsigned short* __restrict__ wtf,
           float* out)
{
    __shared__ float Pt[4 * 16 * 112];
    const int t = threadIdx.x;
    const int lane = t & 63, wid = t >> 6;
    const int frow = lane & 15, fq = lane >> 4;
    const int lb = blockIdx.x, b = blockIdx.y;
    const int l0w = lb * 64 + wid * 16;      // wave's first output row
    const float* xb = x + (size_t)b * SS * DD;

    int gr = l0w + 6 + frow; gr = gr < SS ? gr : SS - 1;
    const float* xp = xb + (size_t)gr * DD + fq * 8;

    f32x4 acc[KK];
#pragma unroll
    for (int i = 0; i < KK; ++i) acc[i] = (f32x4)0.f;

#pragma unroll 4
    for (int ks = 0; ks < 32; ++ks) {
        float4 a0 = *(const float4*)(xp + ks * 32);
        float4 a1 = *(const float4*)(xp + ks * 32 + 4);
        uint4 uu = make_uint4(bfpack(a0.x, a0.y), bfpack(a0.z, a0.w),
                              bfpack(a1.x, a1.y), bfpack(a1.z, a1.w));
        bf16x8 af = __builtin_bit_cast(bf16x8, uu);
#pragma unroll
        for (int i = 0; i < KK; ++i) {
            bf16x8 bf;
            if constexpr (WSOK) {
                bf = *(const bf16x8*)(wtf + (size_t)((i * 32 + ks) * 64 + lane) * 8);
            } else {
                const float* wp = W + (size_t)(ks * 32 + fq * 8) * NO + i * 16 + frow;
                short e0 = (short)f2bf(wp[0 * NO]), e1 = (short)f2bf(wp[1 * NO]);
                short e2 = (short)f2bf(wp[2 * NO]), e3 = (short)f2bf(wp[3 * NO]);
                short e4 = (short)f2bf(wp[4 * NO]), e5 = (short)f2bf(wp[5 * NO]);
                short e6 = (short)f2bf(wp[6 * NO]), e7 = (short)f2bf(wp[7 * NO]);
                bf = bf16x8{e0, e1, e2, e3, e4, e5, e6, e7};
            }
            acc[i] = __builtin_amdgcn_mfma_f32_16x16x32_bf16(af, bf, acc[i], 0, 0, 0);
        }
    }

    // softmax over i per (row = fq*4+reg, h = frow); 1/7 folded
    float* Pw = Pt + wid * (16 * 112);
#pragma unroll
    for (int reg = 0; reg < 4; ++reg) {
        float v[KK];
        float m = -1e30f;
#pragma unroll
        for (int i = 0; i < KK; ++i) {
            v[i] = acc[i][reg] + bias[i * 16 + frow];
            m = fmaxf(m, v[i]);
        }
        float ssum = 0.f;
#pragma unroll
        for (int i = 0; i < KK; ++i) { v[i] = __expf(v[i] - m); ssum += v[i]; }
        float inv = 1.f / (7.f * ssum);
#pragma unroll
        for (int i = 0; i < KK; ++i)
            Pw[(fq * 4 + reg) * 112 + i * 16 + frow] = v[i] * inv;
    }
    // wave-private transpose readback -> coalesced P store into out[b][l][0:112]
    const int srow = lane >> 2, soff = (lane & 3) * 28;
    const int gl = l0w + srow;
    if (gl < LL) {
        float* dst = out + ((size_t)b * LL + gl) * DD + soff;
        const float* src = Pw + srow * 112 + soff;
#pragma unroll
        for (int s = 0; s < 7; ++s)
            *(float4*)(dst + s * 4) = *(const float4*)(src + s * 4);
    }
}

// conv: block = 256 thr, 8 rows x 1024 d. LDS: 8*112 f32 = 3584 B.
__global__ __launch_bounds__(256, 4)
void conv(const float* __restrict__ x, float* out)
{
    __shared__ float Ps[8 * 112];
    const int t = threadIdx.x;
    const int g = blockIdx.x, b = blockIdx.y;
    const int l0 = g * 8;
    const float* xb = x + (size_t)b * SS * DD;

    // conv x loads first (independent of P staging)
    const int d0 = t << 2;
    float4 cx[14];
#pragma unroll
    for (int j = 0; j < 14; ++j) {
        int gr = l0 + j; gr = gr < SS ? gr : SS - 1;
        cx[j] = *(const float4*)(xb + (size_t)gr * DD + d0);
    }
    // stage P rows l0..l0+7 from out[b][l][0:112]: 8 rows (t>>5) x 28 float4
    {
        int row = t >> 5, rem = t & 31;
        if (rem < 28) {
            int pr = l0 + row; pr = pr < LL ? pr : LL - 1;
            *(float4*)(Ps + row * 112 + rem * 4) =
                *(const float4*)(out + ((size_t)b * LL + pr) * DD + rem * 4);
        }
    }
    __syncthreads();

    const int hs = (t & 3) << 2;
#pragma unroll
    for (int q = 0; q < 8; ++q) {
        int l = l0 + q;
        if (l < LL) {
            f32x4 o = (f32x4)0.f;
#pragma unroll
            for (int k = 0; k < KK; ++k) {
                f32x4 pv = *(const f32x4*)(Ps + q * 112 + k * 16 + hs);
                f32x4 xv = { cx[q + k].x, cx[q + k].y, cx[q + k].z, cx[q + k].w };
                o += pv * xv;
            }
            *(f32x4*)(out + ((size_t)b * LL + l) * DD + d0) = o;
        }
    }
}

extern "C" void kernel_launch(void* const* d_in, const int* in_sizes, int n_in,
                              void* d_out, int out_size, void* d_ws, size_t ws_size,
                              hipStream_t stream) {
    const float* x    = (const float*)d_in[0];
    const float* W    = (const float*)d_in[1];
    const float* bias = (const float*)d_in[2];
    float* out        = (float*)d_out;
    const bool wsok = (ws_size >= (size_t)WTF_BYTES) && d_ws != nullptr;
    dim3 ggrid((2048 / 64), 8);              // 32 x 8; waves cover rows 0..2047, stores guarded
    dim3 cgrid((LL + 7) / 8, 8);             // 256 x 8
    if (wsok) {
        unsigned short* wtf = (unsigned short*)d_ws;
        wprep<<<224, 64, 0, stream>>>(W, wtf);
        pgemm<true><<<ggrid, 256, 0, stream>>>(x, W, bias, wtf, out);
    } else {
        pgemm<false><<<ggrid, 256, 0, stream>>>(x, W, bias, nullptr, out);
    }
    conv<<<cgrid, 256, 0, stream>>>(x, out);
}

// Round 9
// 54.385 us; speedup vs baseline: 1.1050x; 1.1050x over previous
//
#include <hip/hip_runtime.h>

// Dynamic lightweight convolution. B=8, S=2048, D=1024, K=7, H=16, L=2042.
// Fused kernel (R6 structure) + pinned conv-prefetch registers:
//   issue stage-A loads + conv-x loads (14 float4) -> LDS-write A -> barrier
//   -> PIN cx in regs (asm keep-alive; barrier already drained vmcnt)
//   -> waves 0..6 MFMA one n-tile each -> logits -> softmax -> P
//   -> conv = pure LDS(P) + FMA on pinned cx + store.

#define KK 7
#define HH 16
#define DD 1024
#define SS 2048
#define LL 2042
#define NO 112
#define TL 16
#define WTF_BYTES (7 * 32 * 64 * 8 * 2)      // 229376

typedef __attribute__((ext_vector_type(8))) short bf16x8;
typedef __attribute__((ext_vector_type(4))) float f32x4;

__device__ __forceinline__ unsigned short f2bf(float f) {
    unsigned u = __builtin_bit_cast(unsigned, f);
    u += 0x7fffu + ((u >> 16) & 1u);         // RNE
    return (unsigned short)(u >> 16);
}
__device__ __forceinline__ unsigned bfpack(float lo, float hi) {
    return (unsigned)f2bf(lo) | ((unsigned)f2bf(hi) << 16);
}

__global__ void wprep(const float* __restrict__ W, unsigned short* __restrict__ wtf) {
    const int bx = blockIdx.x;               // 0..223 = i*32 + ks
    const int lane = threadIdx.x;
    const int i = bx >> 5, ks = bx & 31;
    const int frow = lane & 15, fq = lane >> 4;
    const int col = i * 16 + frow;
    const int k0 = ks * 32 + fq * 8;
    unsigned p[4];
#pragma unroll
    for (int j = 0; j < 4; ++j) {
        float a = W[(size_t)(k0 + 2 * j) * NO + col];
        float b = W[(size_t)(k0 + 2 * j + 1) * NO + col];
        p[j] = bfpack(a, b);
    }
    *(uint4*)(wtf + (size_t)(bx * 64 + lane) * 8) = make_uint4(p[0], p[1], p[2], p[3]);
}

// LDS (32768 B):
//   phase 1-2: A bf16 [16][1024] XOR-swizzled, rows at 2048 B stride
//   phase 3+ (A dead): Lg f32 [16][116] @0 ; P f32 [16][7][16] @8192
template <bool WSOK>
__global__ __launch_bounds__(512, 2)
void dlconv(const float* __restrict__ x, const float* __restrict__ W,
            const float* __restrict__ bias, const unsigned short* __restrict__ wtf,
            float* __restrict__ out)
{
    __shared__ __align__(16) unsigned char smem[32768];
    float* Lg = (float*)smem;                // [16][116]
    float* P  = (float*)(smem + 8192);       // [16][7][16]
    const int t  = threadIdx.x;
    const int lb = blockIdx.x, b = blockIdx.y;
    const int l0 = lb * TL;
    const float* xb = x + (size_t)b * SS * DD;

    // conv-thread mapping: row-group rg (8 rows), channel block d0 (float4)
    const int rg = t >> 8;                   // 0..1
    const int cc = t & 255;                  // 0..255
    const int d0 = cc << 2;                  // 0..1020
    const int hs = (cc & 3) << 2;            // P h-slice offset (floats)

    // ---- 1) stage-A loads -> regs (rows l0+6..l0+21, all K) ----
    float4 sx[8];
#pragma unroll
    for (int s = 0; s < 8; ++s) {
        int idx = t + 512 * s;               // 16 rows x 256 float4
        int row = idx >> 8, c4 = idx & 255;
        int gr = l0 + 6 + row; gr = gr < SS ? gr : SS - 1;
        sx[s] = *(const float4*)(xb + (size_t)gr * DD + c4 * 4);
    }
    // ---- 2) conv x prefetch: rows l0+rg*8 .. +13 ----
    float4 cx[14];
#pragma unroll
    for (int j = 0; j < 14; ++j) {
        int gr = l0 + rg * 8 + j; gr = gr < SS ? gr : SS - 1;
        cx[j] = *(const float4*)(xb + (size_t)gr * DD + d0);
    }
    // ---- 3) A -> LDS (bf16, XOR-swizzled) ----
#pragma unroll
    for (int s = 0; s < 8; ++s) {
        int idx = t + 512 * s;
        int row = idx >> 8, c4 = idx & 255;
        int addr = row * 2048 + ((c4 * 8) ^ ((row & 7) << 4));
        *(uint2*)(smem + addr) = make_uint2(bfpack(sx[s].x, sx[s].y), bfpack(sx[s].z, sx[s].w));
    }
    __syncthreads();                         // drains vmcnt(0): cx is complete here

    // ---- pin cx live across GEMM/softmax (forbid load re-sinking) ----
#pragma unroll
    for (int j = 0; j < 14; ++j)
        asm volatile("" : "+v"(cx[j].x), "+v"(cx[j].y), "+v"(cx[j].z), "+v"(cx[j].w));

    // ---- GEMM: wave i (i<7) computes n-tile i (softmax index k=i) ----
    const int lane = t & 63, wid = t >> 6;
    const int frow = lane & 15, fq = lane >> 4;
    f32x4 acc = (f32x4)0.f;
    if (wid < 7) {
#pragma unroll 8
        for (int ks = 0; ks < 32; ++ks) {
            bf16x8 af = *(const bf16x8*)(smem + frow * 2048 +
                                         ((ks * 64 + fq * 16) ^ ((frow & 7) << 4)));
            bf16x8 bf;
            if constexpr (WSOK) {
                bf = *(const bf16x8*)(wtf + (size_t)((wid * 32 + ks) * 64 + lane) * 8);
            } else {
                const float* wp = W + (size_t)(ks * 32 + fq * 8) * NO + wid * 16 + frow;
                short e0 = (short)f2bf(wp[0 * NO]), e1 = (short)f2bf(wp[1 * NO]);
                short e2 = (short)f2bf(wp[2 * NO]), e3 = (short)f2bf(wp[3 * NO]);
                short e4 = (short)f2bf(wp[4 * NO]), e5 = (short)f2bf(wp[5 * NO]);
                short e6 = (short)f2bf(wp[6 * NO]), e7 = (short)f2bf(wp[7 * NO]);
                bf = bf16x8{e0, e1, e2, e3, e4, e5, e6, e7};
            }
            acc = __builtin_amdgcn_mfma_f32_16x16x32_bf16(af, bf, acc, 0, 0, 0);
        }
    }
    __syncthreads();                          // A region dead beyond this point

    // ---- logits (+bias) -> Lg[r][i*16+h], stride 116 ----
    if (wid < 7) {
        float bi = bias[wid * 16 + frow];
#pragma unroll
        for (int reg = 0; reg < 4; ++reg)
            Lg[(fq * 4 + reg) * 116 + wid * 16 + frow] = acc[reg] + bi;
    }
    __syncthreads();

    // ---- softmax over k: thread (r = t>>4, h = t&15), 256 threads ----
    if (t < 256) {
        const int r = t >> 4, h = t & 15;
        float v[KK];
        float m = -1e30f;
#pragma unroll
        for (int i = 0; i < KK; ++i) {
            v[i] = Lg[r * 116 + i * 16 + h];
            m = fmaxf(m, v[i]);
        }
        float ssum = 0.f;
#pragma unroll
        for (int i = 0; i < KK; ++i) { v[i] = __expf(v[i] - m); ssum += v[i]; }
        float inv = 1.f / (7.f * ssum);       // fold mean's 1/7
#pragma unroll
        for (int i = 0; i < KK; ++i) P[(r * KK + i) * 16 + h] = v[i] * inv;
    }
    __syncthreads();

    // ---- conv: out[b,l0+rg*8+q,d0..] = sum_k P[row][k][hs..] * cx[q+k] ----
#pragma unroll
    for (int q = 0; q < 8; ++q) {
        int row = rg * 8 + q;
        if (l0 + row < LL) {
            f32x4 o = (f32x4)0.f;
#pragma unroll
            for (int k = 0; k < KK; ++k) {
                f32x4 pv = *(const f32x4*)(P + (row * KK + k) * 16 + hs);
                f32x4 xv = { cx[q + k].x, cx[q + k].y, cx[q + k].z, cx[q + k].w };
                o += pv * xv;
            }
            *(f32x4*)(out + ((size_t)b * LL + l0 + row) * DD + d0) = o;
        }
    }
}

extern "C" void kernel_launch(void* const* d_in, const int* in_sizes, int n_in,
                              void* d_out, int out_size, void* d_ws, size_t ws_size,
                              hipStream_t stream) {
    const float* x    = (const float*)d_in[0];
    const float* W    = (const float*)d_in[1];
    const float* bias = (const float*)d_in[2];
    float* out        = (float*)d_out;
    dim3 grid((LL + TL - 1) / TL, 8);        // 128 x 8 = 1024 blocks
    const bool wsok = (ws_size >= (size_t)WTF_BYTES) && d_ws != nullptr;
    if (wsok) {
        unsigned short* wtf = (unsigned short*)d_ws;
        wprep<<<224, 64, 0, stream>>>(W, wtf);
        dlconv<true><<<grid, 512, 0, stream>>>(x, W, bias, wtf, out);
    } else {
        dlconv<false><<<grid, 512, 0, stream>>>(x, W, bias, nullptr, out);
    }
}

// Round 10
// 40.528 us; speedup vs baseline: 1.4828x; 1.3419x over previous
//
#include <hip/hip_runtime.h>

// Dynamic lightweight convolution. B=8, S=2048, D=1024, K=7, H=16, L=2042.
// Fused, single-pass-over-x design:
//   stage x rows l0..l0+21 (bf16, XOR-swz, 45KB LDS) -> waves 0..6 MFMA one
//   n-tile each (A = LDS rows 6..21) -> logits -> softmax (regs) -> P overlaid
//   on Lg -> conv reads x from the SAME LDS tile (rows 0..21) + P, stores out.
// x hits HBM exactly once; conv phase has zero global loads.

#define KK 7
#define HH 16
#define DD 1024
#define SS 2048
#define LL 2042
#define NO 112
#define TL 16
#define WTF_BYTES (7 * 32 * 64 * 8 * 2)      // 229376

typedef __attribute__((ext_vector_type(8))) short bf16x8;
typedef __attribute__((ext_vector_type(4))) float f32x4;

__device__ __forceinline__ unsigned short f2bf(float f) {
    unsigned u = __builtin_bit_cast(unsigned, f);
    u += 0x7fffu + ((u >> 16) & 1u);         // RNE
    return (unsigned short)(u >> 16);
}
__device__ __forceinline__ unsigned bfpack(float lo, float hi) {
    return (unsigned)f2bf(lo) | ((unsigned)f2bf(hi) << 16);
}
__device__ __forceinline__ float bflo(unsigned u) {
    return __builtin_bit_cast(float, u << 16);
}
__device__ __forceinline__ float bfhi(unsigned u) {
    return __builtin_bit_cast(float, u & 0xffff0000u);
}

__global__ void wprep(const float* __restrict__ W, unsigned short* __restrict__ wtf) {
    const int bx = blockIdx.x;               // 0..223 = i*32 + ks
    const int lane = threadIdx.x;
    const int i = bx >> 5, ks = bx & 31;
    const int frow = lane & 15, fq = lane >> 4;
    const int col = i * 16 + frow;
    const int k0 = ks * 32 + fq * 8;
    unsigned p[4];
#pragma unroll
    for (int j = 0; j < 4; ++j) {
        float a = W[(size_t)(k0 + 2 * j) * NO + col];
        float b = W[(size_t)(k0 + 2 * j + 1) * NO + col];
        p[j] = bfpack(a, b);
    }
    *(uint4*)(wtf + (size_t)(bx * 64 + lane) * 8) = make_uint4(p[0], p[1], p[2], p[3]);
}

// LDS (52480 B):
//   A  bf16 [22][1024] XOR-swizzled, 2048 B row stride  @ 0 .. 45056
//   Lg f32 [16][116]                                    @ 45056 .. 52480
//   P  f32 [16][7][16] overlaid on Lg after softmax-read barrier
template <bool WSOK>
__global__ __launch_bounds__(512, 2)
void dlconv(const float* __restrict__ x, const float* __restrict__ W,
            const float* __restrict__ bias, const unsigned short* __restrict__ wtf,
            float* __restrict__ out)
{
    __shared__ __align__(16) unsigned char smem[52480];
    float* Lg = (float*)(smem + 45056);      // [16][116]
    float* P  = (float*)(smem + 45056);      // [16][7][16], overlaid
    const int t  = threadIdx.x;
    const int lb = blockIdx.x, b = blockIdx.y;
    const int l0 = lb * TL;
    const float* xb = x + (size_t)b * SS * DD;

    // ---- stage x rows l0..l0+21, bf16, XOR-swizzled: 22*256 uint2 = 512*11 ----
#pragma unroll
    for (int s = 0; s < 11; ++s) {
        int idx = t + 512 * s;               // 0..5631
        int rr = idx >> 8, c4 = idx & 255;
        int gr = l0 + rr; gr = gr < SS ? gr : SS - 1;
        float4 v = *(const float4*)(xb + (size_t)gr * DD + c4 * 4);
        int addr = rr * 2048 + ((c4 * 8) ^ ((rr & 7) << 4));
        *(uint2*)(smem + addr) = make_uint2(bfpack(v.x, v.y), bfpack(v.z, v.w));
    }
    __syncthreads();

    // ---- GEMM: wave i (i<7) computes n-tile i; A = LDS rows 6..21 ----
    const int lane = t & 63, wid = t >> 6;
    const int frow = lane & 15, fq = lane >> 4;
    f32x4 acc = (f32x4)0.f;
    if (wid < 7) {
        const int arr = 6 + frow;            // LDS row of this lane's A fragment
        const int abase = arr * 2048;
        const int aswz = (arr & 7) << 4;
#pragma unroll 8
        for (int ks = 0; ks < 32; ++ks) {
            bf16x8 af = *(const bf16x8*)(smem + abase + ((ks * 64 + fq * 16) ^ aswz));
            bf16x8 bf;
            if constexpr (WSOK) {
                bf = *(const bf16x8*)(wtf + (size_t)((wid * 32 + ks) * 64 + lane) * 8);
            } else {
                const float* wp = W + (size_t)(ks * 32 + fq * 8) * NO + wid * 16 + frow;
                short e0 = (short)f2bf(wp[0 * NO]), e1 = (short)f2bf(wp[1 * NO]);
                short e2 = (short)f2bf(wp[2 * NO]), e3 = (short)f2bf(wp[3 * NO]);
                short e4 = (short)f2bf(wp[4 * NO]), e5 = (short)f2bf(wp[5 * NO]);
                short e6 = (short)f2bf(wp[6 * NO]), e7 = (short)f2bf(wp[7 * NO]);
                bf = bf16x8{e0, e1, e2, e3, e4, e5, e6, e7};
            }
            acc = __builtin_amdgcn_mfma_f32_16x16x32_bf16(af, bf, acc, 0, 0, 0);
        }
        // logits (+bias) -> Lg[r][wid*16+h], stride 116
        float bi = bias[wid * 16 + frow];
#pragma unroll
        for (int reg = 0; reg < 4; ++reg)
            Lg[(fq * 4 + reg) * 116 + wid * 16 + frow] = acc[reg] + bi;
    }
    __syncthreads();

    // ---- softmax over k: thread (r = t>>4, h = t&15); read->regs, bar, write P ----
    float v[KK];
    if (t < 256) {
        const int r = t >> 4, h = t & 15;
        float m = -1e30f;
#pragma unroll
        for (int i = 0; i < KK; ++i) {
            v[i] = Lg[r * 116 + i * 16 + h];
            m = fmaxf(m, v[i]);
        }
        float ssum = 0.f;
#pragma unroll
        for (int i = 0; i < KK; ++i) { v[i] = __expf(v[i] - m); ssum += v[i]; }
        float inv = 1.f / (7.f * ssum);       // fold mean's 1/7
#pragma unroll
        for (int i = 0; i < KK; ++i) v[i] *= inv;
    }
    __syncthreads();                          // all Lg reads done; safe to overlay P
    if (t < 256) {
        const int r = t >> 4, h = t & 15;
#pragma unroll
        for (int i = 0; i < KK; ++i) P[(r * KK + i) * 16 + h] = v[i];
    }
    __syncthreads();

    // ---- conv: x from LDS (bf16), P from LDS; out[b,l0+row,d0..d0+3] ----
    const int rg = t >> 8;                   // 0..1: rows rg*8 .. rg*8+7
    const int cc = t & 255;                  // column quad 0..255
    const int hs = (cc & 3) << 2;            // P h-slice (floats)
    const int coff = cc * 8;                 // byte offset of this quad in a row
#pragma unroll
    for (int q = 0; q < 8; ++q) {
        int row = rg * 8 + q;
        if (l0 + row < LL) {
            f32x4 o = (f32x4)0.f;
#pragma unroll
            for (int k = 0; k < KK; ++k) {
                int rr = row + k;            // 0..21
                uint2 u = *(const uint2*)(smem + rr * 2048 + (coff ^ ((rr & 7) << 4)));
                f32x4 pv = *(const f32x4*)(P + (row * KK + k) * 16 + hs);
                o.x += pv.x * bflo(u.x);
                o.y += pv.y * bfhi(u.x);
                o.z += pv.z * bflo(u.y);
                o.w += pv.w * bfhi(u.y);
            }
            *(f32x4*)(out + ((size_t)b * LL + l0 + row) * DD + cc * 4) = o;
        }
    }
}

extern "C" void kernel_launch(void* const* d_in, const int* in_sizes, int n_in,
                              void* d_out, int out_size, void* d_ws, size_t ws_size,
                              hipStream_t stream) {
    const float* x    = (const float*)d_in[0];
    const float* W    = (const float*)d_in[1];
    const float* bias = (const float*)d_in[2];
    float* out        = (float*)d_out;
    dim3 grid((LL + TL - 1) / TL, 8);        // 128 x 8 = 1024 blocks
    const bool wsok = (ws_size >= (size_t)WTF_BYTES) && d_ws != nullptr;
    if (wsok) {
        unsigned short* wtf = (unsigned short*)d_ws;
        wprep<<<224, 64, 0, stream>>>(W, wtf);
        dlconv<true><<<grid, 512, 0, stream>>>(x, W, bias, wtf, out);
    } else {
        dlconv<false><<<grid, 512, 0, stream>>>(x, W, bias, nullptr, out);
    }
}

// Round 11
// 36.349 us; speedup vs baseline: 1.6533x; 1.1150x over previous
//
#include <hip/hip_runtime.h>

// Dynamic lightweight convolution. B=8, S=2048, D=1024, K=7, H=16, L=2042.
// Fused, 4-blocks/CU design:
//   stage x rows l0+6..l0+21 (bf16, XOR-swz, 32KB) -> waves 0..6 MFMA one
//   n-tile each -> logits Lg -> softmax IN-PLACE (P overlays Lg, same thread,
//   no extra barrier) -> conv: x from LDS (rows >= l0+6) or global f32
//   (rows l0..l0+5, L3-hot, static-indexed regs), P from Lg; store out.
// LDS 40192 B -> 4 blocks/CU; launch_bounds(512,8) pins VGPR<=64 -> 32 waves/CU.

#define KK 7
#define HH 16
#define DD 1024
#define SS 2048
#define LL 2042
#define NO 112
#define TL 16
#define WTF_BYTES (7 * 32 * 64 * 8 * 2)      // 229376

typedef __attribute__((ext_vector_type(8))) short bf16x8;
typedef __attribute__((ext_vector_type(4))) float f32x4;

__device__ __forceinline__ unsigned short f2bf(float f) {
    unsigned u = __builtin_bit_cast(unsigned, f);
    u += 0x7fffu + ((u >> 16) & 1u);         // RNE
    return (unsigned short)(u >> 16);
}
__device__ __forceinline__ unsigned bfpack(float lo, float hi) {
    return (unsigned)f2bf(lo) | ((unsigned)f2bf(hi) << 16);
}
__device__ __forceinline__ float bflo(unsigned u) {
    return __builtin_bit_cast(float, u << 16);
}
__device__ __forceinline__ float bfhi(unsigned u) {
    return __builtin_bit_cast(float, u & 0xffff0000u);
}

__global__ void wprep(const float* __restrict__ W, unsigned short* __restrict__ wtf) {
    const int bx = blockIdx.x;               // 0..223 = i*32 + ks
    const int lane = threadIdx.x;
    const int i = bx >> 5, ks = bx & 31;
    const int frow = lane & 15, fq = lane >> 4;
    const int col = i * 16 + frow;
    const int k0 = ks * 32 + fq * 8;
    unsigned p[4];
#pragma unroll
    for (int j = 0; j < 4; ++j) {
        float a = W[(size_t)(k0 + 2 * j) * NO + col];
        float b = W[(size_t)(k0 + 2 * j + 1) * NO + col];
        p[j] = bfpack(a, b);
    }
    *(uint4*)(wtf + (size_t)(bx * 64 + lane) * 8) = make_uint4(p[0], p[1], p[2], p[3]);
}

// LDS (40192 B):
//   A  bf16 [16][1024] XOR-swizzled (rows = x rows l0+6..l0+21) @ 0 .. 32768
//   Lg f32 [16][116] @ 32768 .. 40192 ; P overlaid in-place after softmax
template <bool WSOK>
__global__ __launch_bounds__(512, 8)
void dlconv(const float* __restrict__ x, const float* __restrict__ W,
            const float* __restrict__ bias, const unsigned short* __restrict__ wtf,
            float* __restrict__ out)
{
    __shared__ __align__(16) unsigned char smem[40192];
    float* Lg = (float*)(smem + 32768);      // [16][116]; becomes P in-place
    const int t  = threadIdx.x;
    const int lb = blockIdx.x, b = blockIdx.y;
    const int l0 = lb * TL;
    const float* xb = x + (size_t)b * SS * DD;

    // ---- stage x rows l0+6..l0+21 -> LDS rows 0..15 (bf16, XOR-swizzled) ----
#pragma unroll
    for (int s = 0; s < 8; ++s) {
        int idx = t + 512 * s;               // 0..4095 = 16 rows x 256 float4
        int row = idx >> 8, c4 = idx & 255;
        int gr = l0 + 6 + row; gr = gr < SS ? gr : SS - 1;
        float4 v = *(const float4*)(xb + (size_t)gr * DD + c4 * 4);
        int addr = row * 2048 + ((c4 * 8) ^ ((row & 7) << 4));
        *(uint2*)(smem + addr) = make_uint2(bfpack(v.x, v.y), bfpack(v.z, v.w));
    }
    __syncthreads();

    // ---- GEMM: wave i (i<7) computes n-tile i (softmax index k=i) ----
    const int lane = t & 63, wid = t >> 6;
    const int frow = lane & 15, fq = lane >> 4;
    if (wid < 7) {
        const int abase = frow * 2048;
        const int aswz = (frow & 7) << 4;
        f32x4 acc = (f32x4)0.f;
#pragma unroll 8
        for (int ks = 0; ks < 32; ++ks) {
            bf16x8 af = *(const bf16x8*)(smem + abase + ((ks * 64 + fq * 16) ^ aswz));
            bf16x8 bf;
            if constexpr (WSOK) {
                bf = *(const bf16x8*)(wtf + (size_t)((wid * 32 + ks) * 64 + lane) * 8);
            } else {
                const float* wp = W + (size_t)(ks * 32 + fq * 8) * NO + wid * 16 + frow;
                short e0 = (short)f2bf(wp[0 * NO]), e1 = (short)f2bf(wp[1 * NO]);
                short e2 = (short)f2bf(wp[2 * NO]), e3 = (short)f2bf(wp[3 * NO]);
                short e4 = (short)f2bf(wp[4 * NO]), e5 = (short)f2bf(wp[5 * NO]);
                short e6 = (short)f2bf(wp[6 * NO]), e7 = (short)f2bf(wp[7 * NO]);
                bf = bf16x8{e0, e1, e2, e3, e4, e5, e6, e7};
            }
            acc = __builtin_amdgcn_mfma_f32_16x16x32_bf16(af, bf, acc, 0, 0, 0);
        }
        float bi = bias[wid * 16 + frow];
#pragma unroll
        for (int reg = 0; reg < 4; ++reg)
            Lg[(fq * 4 + reg) * 116 + wid * 16 + frow] = acc[reg] + bi;
    }
    __syncthreads();

    // ---- softmax over k, in-place (thread owns its 7 slots; no extra bar) ----
    if (t < 256) {
        const int r = t >> 4, h = t & 15;
        float v[KK];
        float m = -1e30f;
#pragma unroll
        for (int i = 0; i < KK; ++i) {
            v[i] = Lg[r * 116 + i * 16 + h];
            m = fmaxf(m, v[i]);
        }
        float ssum = 0.f;
#pragma unroll
        for (int i = 0; i < KK; ++i) { v[i] = __expf(v[i] - m); ssum += v[i]; }
        float inv = 1.f / (7.f * ssum);       // fold mean's 1/7
#pragma unroll
        for (int i = 0; i < KK; ++i) Lg[r * 116 + i * 16 + h] = v[i] * inv;
    }
    __syncthreads();

    // ---- conv: out[b,l0+row,d] = sum_k P[row][k][d%16] * x[b,l0+row+k,d] ----
    // rg=0 waves: out rows 0..7 (x rows 0..13: rows 0..5 from GLOBAL f32,
    //             rows 6..13 from LDS). rg=1 waves: out rows 8..15, all LDS.
    const int rg = t >> 8;                   // wave-uniform
    const int cc = t & 255;
    const int hs = (cc & 3) << 2;
    const int coff = cc * 8;                 // byte offset in an LDS row
    float* orow0 = out + ((size_t)b * LL + l0) * DD + cc * 4;

    if (rg == 0) {
        f32x4 gx[6];
#pragma unroll
        for (int j = 0; j < 6; ++j)
            gx[j] = *(const f32x4*)(xb + (size_t)(l0 + j) * DD + cc * 4);
#pragma unroll
        for (int q = 0; q < 8; ++q) {
            f32x4 o = (f32x4)0.f;
#pragma unroll
            for (int k = 0; k < KK; ++k) {
                f32x4 pv = *(const f32x4*)(Lg + q * 116 + k * 16 + hs);
                if (q + k < 6) {
                    o += pv * gx[q + k];     // compile-time index
                } else {
                    int rr = q + k - 6;      // LDS row 0..9
                    uint2 u = *(const uint2*)(smem + rr * 2048 + (coff ^ ((rr & 7) << 4)));
                    f32x4 xv = { bflo(u.x), bfhi(u.x), bflo(u.y), bfhi(u.y) };
                    o += pv * xv;
                }
            }
            *(f32x4*)(orow0 + (size_t)q * DD) = o;
        }
    } else {
#pragma unroll
        for (int q = 0; q < 8; ++q) {
            int row = 8 + q;
            if (l0 + row < LL) {
                f32x4 o = (f32x4)0.f;
#pragma unroll
                for (int k = 0; k < KK; ++k) {
                    int rr = row + k - 6;    // LDS row 2..15
                    f32x4 pv = *(const f32x4*)(Lg + row * 116 + k * 16 + hs);
                    uint2 u = *(const uint2*)(smem + rr * 2048 + (coff ^ ((rr & 7) << 4)));
                    f32x4 xv = { bflo(u.x), bfhi(u.x), bflo(u.y), bfhi(u.y) };
                    o += pv * xv;
                }
                *(f32x4*)(orow0 + (size_t)row * DD) = o;
            }
        }
    }
}

extern "C" void kernel_launch(void* const* d_in, const int* in_sizes, int n_in,
                              void* d_out, int out_size, void* d_ws, size_t ws_size,
                              hipStream_t stream) {
    const float* x    = (const float*)d_in[0];
    const float* W    = (const float*)d_in[1];
    const float* bias = (const float*)d_in[2];
    float* out        = (float*)d_out;
    dim3 grid((LL + TL - 1) / TL, 8);        // 128 x 8 = 1024 blocks = 4/CU exactly
    const bool wsok = (ws_size >= (size_t)WTF_BYTES) && d_ws != nullptr;
    if (wsok) {
        unsigned short* wtf = (unsigned short*)d_ws;
        wprep<<<224, 64, 0, stream>>>(W, wtf);
        dlconv<true><<<grid, 512, 0, stream>>>(x, W, bias, wtf, out);
    } else {
        dlconv<false><<<grid, 512, 0, stream>>>(x, W, bias, nullptr, out);
    }
}